// Round 13
// baseline (2665.921 us; speedup 1.0000x reference)
//
#include <hip/hip_runtime.h>
#include <cstddef>
#include <cstdint>

constexpr int kSeq = 512;
constexpr int kH   = 256;   // hidden per direction
constexpr int kG   = 1024;  // 4*kH (gates)
constexpr int kE   = 320;   // embed dim
constexpr int kLH  = 512;   // 2*kH
constexpr int kMLP = 512;

typedef _Float16 h2 __attribute__((ext_vector_type(2)));

__device__ __forceinline__ float fexp2f(float x) {
  float r; asm("v_exp_f32 %0, %1" : "=v"(r) : "v"(x)); return r;
}
__device__ __forceinline__ float frcpf(float x) {
  float r; asm("v_rcp_f32 %0, %1" : "=v"(r) : "v"(x)); return r;
}
__device__ __forceinline__ float sigm(float x) {
  return frcpf(1.0f + fexp2f(-1.4426950408889634f * x));
}
__device__ __forceinline__ float tanh_(float x) {
  // tanh(x) = 1 - 2/(1+e^{2x}); e^{2x} = 2^(x*2*log2(e)). inf-safe at both ends.
  return 1.0f - 2.0f * frcpf(1.0f + fexp2f(2.8853900817779268f * x));
}

__device__ __forceinline__ float fdot2(unsigned int w, unsigned int h, float c) {
#if __has_builtin(__builtin_amdgcn_fdot2)
  return __builtin_amdgcn_fdot2(__builtin_bit_cast(h2, w),
                                __builtin_bit_cast(h2, h), c, false);
#else
  const h2 wv = __builtin_bit_cast(h2, w);
  const h2 hv = __builtin_bit_cast(h2, h);
  return c + (float)wv.x * (float)hv.x + (float)wv.y * (float)hv.y;
#endif
}

__device__ __forceinline__ unsigned int packh2(float a, float b) {
  h2 v; v.x = (_Float16)a; v.y = (_Float16)b;
  return __builtin_bit_cast(unsigned int, v);
}

// sc0-only comm ops: write-through/read at the XCD-shared L2 (fast path when
// producer+consumer share an XCD). Deadlock-safety comes from the agent-slot
// fallback, never from these.
__device__ __forceinline__ void store_l2(float* p, float v) {
  asm volatile("global_store_dword %0, %1, off sc0" :: "v"(p), "v"(v) : "memory");
}
__device__ __forceinline__ float load_l2(const float* p) {
  float r;
  asm volatile("global_load_dword %0, %1, off sc0\n\ts_waitcnt vmcnt(0)"
               : "=v"(r) : "v"(p) : "memory");
  return r;
}

// ---------------- embedding gather ----------------
__global__ void embed_k(const int* __restrict__ wt, const int* __restrict__ pt,
                        const float* __restrict__ we, const float* __restrict__ pe,
                        float* __restrict__ X) {
  const int t = blockIdx.x;
  const int c = threadIdx.x;  // 0..319
  const int w = wt[t];
  const int p = pt[t];
  X[t * kE + c] = (c < 256) ? we[(size_t)w * 256 + c] : pe[p * 64 + (c - 256)];
}

// ---------------- Whh f32 -> packed f16 (both layers, full GPU) ----------------
__global__ __launch_bounds__(256) void pack_wh_k(
    const float* __restrict__ whh0, const float* __restrict__ whh1,
    unsigned int* __restrict__ wh16) {
  const int idx = blockIdx.x * 256 + threadIdx.x;   // 0 .. 2*262144-1
  const int layer = idx >> 18;
  const int li = idx & 262143;
  const int rowg = li >> 7;                         // d*1024 + row
  const int c2 = li & 127;
  const float* src = (layer ? whh1 : whh0) + (size_t)rowg * kH + c2 * 2;
  wh16[idx] = packh2(src[0], src[1]);
}

// ---------------- generic f32 "NT" GEMM ----------------
template <int BM, int BN, int BK>
__global__ __launch_bounds__(256) void gemm_nt(
    const float* __restrict__ A, int lda,
    const float* __restrict__ B, int ldb,
    const float* __restrict__ b1, const float* __restrict__ b2, float scale,
    float* __restrict__ C, int csm, int csn, int K) {
  const int tid = threadIdx.x;
  const int m0 = blockIdx.y * BM;
  const int n0 = blockIdx.x * BN;
  __shared__ float As[BK][BM];
  __shared__ float Bs[BK][BN];
  const int lm = tid >> 2;
  const int lk = tid & 3;
  const int tx = tid & 15;
  const int ty = tid >> 4;
  float acc[4][4] = {};
  for (int k0 = 0; k0 < K; k0 += BK) {
    const float4 av = *(const float4*)(A + (size_t)(m0 + lm) * lda + k0 + lk * 4);
    const float4 bv = *(const float4*)(B + (size_t)(n0 + lm) * ldb + k0 + lk * 4);
    __syncthreads();
    As[lk * 4 + 0][lm] = av.x; As[lk * 4 + 1][lm] = av.y;
    As[lk * 4 + 2][lm] = av.z; As[lk * 4 + 3][lm] = av.w;
    Bs[lk * 4 + 0][lm] = bv.x; Bs[lk * 4 + 1][lm] = bv.y;
    Bs[lk * 4 + 2][lm] = bv.z; Bs[lk * 4 + 3][lm] = bv.w;
    __syncthreads();
#pragma unroll
    for (int kk = 0; kk < BK; ++kk) {
      const float4 a = *(const float4*)&As[kk][ty * 4];
      const float4 b = *(const float4*)&Bs[kk][tx * 4];
      acc[0][0] = fmaf(a.x, b.x, acc[0][0]);
      acc[0][1] = fmaf(a.x, b.y, acc[0][1]);
      acc[0][2] = fmaf(a.x, b.z, acc[0][2]);
      acc[0][3] = fmaf(a.x, b.w, acc[0][3]);
      acc[1][0] = fmaf(a.y, b.x, acc[1][0]);
      acc[1][1] = fmaf(a.y, b.y, acc[1][1]);
      acc[1][2] = fmaf(a.y, b.z, acc[1][2]);
      acc[1][3] = fmaf(a.y, b.w, acc[1][3]);
      acc[2][0] = fmaf(a.z, b.x, acc[2][0]);
      acc[2][1] = fmaf(a.z, b.y, acc[2][1]);
      acc[2][2] = fmaf(a.z, b.z, acc[2][2]);
      acc[2][3] = fmaf(a.z, b.w, acc[2][3]);
      acc[3][0] = fmaf(a.w, b.x, acc[3][0]);
      acc[3][1] = fmaf(a.w, b.y, acc[3][1]);
      acc[3][2] = fmaf(a.w, b.z, acc[3][2]);
      acc[3][3] = fmaf(a.w, b.w, acc[3][3]);
    }
  }
#pragma unroll
  for (int ii = 0; ii < 4; ++ii) {
#pragma unroll
    for (int jj = 0; jj < 4; ++jj) {
      const int m = m0 + ty * 4 + ii;
      const int n = n0 + tx * 4 + jj;
      float v = acc[ii][jj];
      if (b1) v += b1[n];
      if (b2) v += b2[n];
      C[(size_t)m * csm + (size_t)n * csn] = v * scale;
    }
  }
}

// ---------------- 2-CU-per-direction LSTM scan, L2-routed comm ----------------
// r12 structure (poll-overlaps-production, XCD co-location via blockIdx%8
// heuristic: workers bx in {0,8} d=0 / {1,9} d=1) with DUAL-PATH h exchange:
//   producer: sc0 store to fast slot (lands in the XCD-shared L2) +
//             agent-scope atomic store to agent slot (proven visible path)
//   poller:   spin on fast slot with sc0 loads (L2 RT ~250cy when co-located);
//             every 16th iteration also check the agent slot (fallback, makes
//             the protocol correct for ANY block placement).
// Data-as-flag: fresh slot/step, h+2.0 never 0 bits. 2 barriers/step.
__global__ __launch_bounds__(1024)
__attribute__((amdgpu_waves_per_eu(4, 4)))
void lstm_scan_2cu(
    const unsigned int* __restrict__ wh16,  // (2,1024,128) packed f16 pairs
    const float* __restrict__ pre,          // (2, kSeq, kG) pregates
    float* __restrict__ out,                // (kSeq, kLH)
    float* __restrict__ commF,              // (2, kSeq, kH) fast slots, zeroed
    float* __restrict__ commA)              // (2, kSeq, kH) agent slots, zeroed
{
  const int bx = blockIdx.x;
  int d, s;
  if (bx == 0)      { d = 0; s = 0; }
  else if (bx == 1) { d = 1; s = 0; }
  else if (bx == 8) { d = 0; s = 1; }
  else if (bx == 9) { d = 1; s = 1; }
  else return;                         // co-location dummies exit

  const int t = threadIdx.x;
  const int w = t >> 6;
  const int L = t & 63;
  const int ch = w & 1;                 // column-half
  const int r  = (w >> 1) * 64 + L;     // local row 0..511  (= g*128 + j)
  const int g  = r >> 7;
  const int j  = r & 127;
  const int grow = g * kH + s * 128 + j;

  uint4 wr[16];                         // cols [ch*128, +128) of row grow
  {
    const uint4* wp = (const uint4*)wh16 + ((size_t)d * kG + grow) * 32 + ch * 16;
#pragma unroll
    for (int k = 0; k < 16; ++k) wr[k] = wp[k];
  }

  __shared__ __align__(16) _Float16 hh16[kH];  // h(u-1), both halves
  __shared__ float pbuf[2][512];
  if (t < 128) ((h2*)hh16)[t] = h2{(_Float16)0.f, (_Float16)0.f};
  float c = 0.0f;
  __syncthreads();

  const uint4* hh4 = (const uint4*)hh16;
  float* cmF = commF + (size_t)d * kSeq * kH;
  float* cmA = commA + (size_t)d * kSeq * kH;
  const bool isGate = (t < 128);
  const bool isPoll = (t >= 512 && t < 640);
  const int re = (1 - s) * 128 + (t - 512);    // element polled (valid if isPoll)

  for (int u = 0; u < kSeq; ++u) {
    const int ts = d ? (kSeq - 1 - u) : u;
    // gate threads: issue this step's 4 pregate loads; resolve under the dot
    float pg0 = 0.f, pg1 = 0.f, pg2 = 0.f, pg3 = 0.f;
    if (isGate) {
      const float* pp = pre + ((size_t)d * kSeq + ts) * kG + s * 128 + t;
      pg0 = pp[0]; pg1 = pp[256]; pg2 = pp[512]; pg3 = pp[768];
    }
    // ---- Phase A: all 16 waves dot their column-half of h(u-1) ----
    {
      const uint4* hp = hh4 + ch * 16;
      float a0 = 0.f, a1 = 0.f, a2 = 0.f, a3 = 0.f;
#pragma unroll
      for (int k = 0; k < 16; ++k) {
        const uint4 hv = hp[k];      // wave-uniform LDS broadcast
        a0 = fdot2(wr[k].x, hv.x, a0);
        a1 = fdot2(wr[k].y, hv.y, a1);
        a2 = fdot2(wr[k].z, hv.z, a2);
        a3 = fdot2(wr[k].w, hv.w, a3);
      }
      pbuf[ch][r] = (a0 + a1) + (a2 + a3);
    }
    __syncthreads();   // Sa: partials complete

    // ---- Phase B: gates (own half) || poll peer's h(u) (remote half) ----
    if (isGate) {
      const float gi = pbuf[0][t]       + pbuf[1][t]       + pg0;
      const float gf = pbuf[0][128 + t] + pbuf[1][128 + t] + pg1;
      const float gg = pbuf[0][256 + t] + pbuf[1][256 + t] + pg2;
      const float go = pbuf[0][384 + t] + pbuf[1][384 + t] + pg3;
      const float iv = sigm(gi), fv = sigm(gf);
      const float gv = tanh_(gg), ov = sigm(go);
      c = fv * c + iv * gv;
      const float h = ov * tanh_(c);
      const int e = s * 128 + t;
      const float hv2 = h + 2.0f;
      store_l2(&cmF[(size_t)u * kH + e], hv2);       // fast slot (shared L2)
      __hip_atomic_store(&cmA[(size_t)u * kH + e], hv2,
                         __ATOMIC_RELAXED, __HIP_MEMORY_SCOPE_AGENT);  // fallback
      hh16[e] = (_Float16)h;
      out[(size_t)ts * kLH + d * kH + e] = h;
    } else if (isPoll) {
      const float* srcF = &cmF[(size_t)u * kH + re];
      const float* srcA = &cmA[(size_t)u * kH + re];
      float v = 0.0f;
      int it = 0;
      for (;;) {
        float a = load_l2(srcF);               // fast path: XCD-shared L2
        if (a != 0.0f) { v = a; break; }
        if ((++it & 15) == 0) {                // fallback: agent-visible slot
          a = __hip_atomic_load(srcA, __ATOMIC_RELAXED, __HIP_MEMORY_SCOPE_AGENT);
          if (a != 0.0f) { v = a; break; }
        }
      }
      hh16[re] = (_Float16)(v - 2.0f);
    }
    __syncthreads();   // Sb: hh16 = complete h(u)
  }
}

// ---------------- pair scorer ----------------
__global__ __launch_bounds__(512) void score_k(
    const float* __restrict__ Up, const float* __restrict__ VT,
    const float* __restrict__ wout, const float* __restrict__ bout,
    float* __restrict__ out) {
  const int i = blockIdx.x;
  const int j = threadIdx.x;
  __shared__ float u_sh[kMLP];
  __shared__ float w_sh[kMLP];
  u_sh[j] = Up[(size_t)i * kMLP + j];
  w_sh[j] = wout[j];
  __syncthreads();
  float acc = 0.0f;
#pragma unroll 4
  for (int m = 0; m < kMLP; ++m) {
    const float x = u_sh[m] + VT[(size_t)m * kSeq + j];  // pre-scaled by 2*log2e
    const float th = 1.0f - 2.0f * frcpf(1.0f + fexp2f(x));
    acc = fmaf(th, w_sh[m], acc);
  }
  const float s = acc + bout[0];
  out[(size_t)i * kSeq + j] = (j == i) ? 0.0f : s;
}

extern "C" void kernel_launch(void* const* d_in, const int* in_sizes, int n_in,
                              void* d_out, int out_size, void* d_ws, size_t ws_size,
                              hipStream_t stream) {
  const int*   wt   = (const int*)d_in[0];
  const int*   pt   = (const int*)d_in[1];
  const float* wemb = (const float*)d_in[2];
  const float* pemb = (const float*)d_in[3];
  const float* wih0 = (const float*)d_in[4];
  const float* whh0 = (const float*)d_in[5];
  const float* bih0 = (const float*)d_in[6];
  const float* bhh0 = (const float*)d_in[7];
  const float* wih1 = (const float*)d_in[8];
  const float* whh1 = (const float*)d_in[9];
  const float* bih1 = (const float*)d_in[10];
  const float* bhh1 = (const float*)d_in[11];
  const float* wlin = (const float*)d_in[12];
  const float* blin = (const float*)d_in[13];
  const float* wout = (const float*)d_in[14];
  const float* bout = (const float*)d_in[15];
  float* outp = (float*)d_out;

  float* ws   = (float*)d_ws;
  float* X    = ws;                      // 512*320
  float* PG0  = X + kSeq * kE;           // 2*512*1024
  float* X1   = PG0 + 2 * kSeq * kG;     // 512*512
  float* PG1  = X1 + kSeq * kLH;         // 2*512*1024
  float* LOUT = PG1 + 2 * kSeq * kG;     // 512*512
  float* U    = LOUT + kSeq * kLH;       // 512*512
  float* VT   = U + kSeq * kMLP;         // 512*512
  float* C0F  = VT + kSeq * kMLP;        // 2*512*256 fast slots, layer 0
  float* C0A  = C0F + 2 * kSeq * kH;     // 2*512*256 agent slots, layer 0
  float* C1F  = C0A + 2 * kSeq * kH;     // layer 1 fast
  float* C1A  = C1F + 2 * kSeq * kH;     // layer 1 agent
  unsigned int* WH16 = (unsigned int*)(C1A + 2 * kSeq * kH);  // 2*262144

  const float SC = 2.8853900817779268f;  // 2*log2(e), folds tanh scaling

  // zero all comm slots (data-as-flag; fresh slot per step)
  hipMemsetAsync(C0F, 0, 4 * 2 * kSeq * kH * sizeof(float), stream);

  embed_k<<<kSeq, kE, 0, stream>>>(wt, pt, wemb, pemb, X);
  pack_wh_k<<<2048, 256, 0, stream>>>(whh0, whh1, WH16);

  for (int d = 0; d < 2; ++d) {
    gemm_nt<64, 64, 16><<<dim3(kG / 64, kSeq / 64), 256, 0, stream>>>(
        X, kE, wih0 + (size_t)d * kG * kE, kE,
        bih0 + d * kG, bhh0 + d * kG, 1.0f,
        PG0 + (size_t)d * kSeq * kG, kG, 1, kE);
  }
  lstm_scan_2cu<<<10, 1024, 0, stream>>>(WH16, PG0, X1, C0F, C0A);

  for (int d = 0; d < 2; ++d) {
    gemm_nt<64, 64, 16><<<dim3(kG / 64, kSeq / 64), 256, 0, stream>>>(
        X1, kLH, wih1 + (size_t)d * kG * kLH, kLH,
        bih1 + d * kG, bhh1 + d * kG, 1.0f,
        PG1 + (size_t)d * kSeq * kG, kG, 1, kLH);
  }
  lstm_scan_2cu<<<10, 1024, 0, stream>>>(WH16 + 2 * kG * 128, PG1, LOUT, C1F, C1A);

  gemm_nt<64, 64, 16><<<dim3(kMLP / 64, kSeq / 64), 256, 0, stream>>>(
      LOUT, kLH, wlin, 2 * kLH, nullptr, nullptr, SC,
      U, kMLP, 1, kLH);
  gemm_nt<64, 64, 16><<<dim3(kMLP / 64, kSeq / 64), 256, 0, stream>>>(
      LOUT, kLH, wlin + kLH, 2 * kLH, blin, nullptr, SC,
      VT, 1, kSeq, kLH);

  score_k<<<kSeq, 512, 0, stream>>>(U, VT, wout, bout, outp);
}

// Round 14
// 1891.070 us; speedup vs baseline: 1.4097x; 1.4097x over previous
//
#include <hip/hip_runtime.h>
#include <cstddef>
#include <cstdint>

constexpr int kSeq = 512;
constexpr int kH   = 256;   // hidden per direction
constexpr int kG   = 1024;  // 4*kH (gates)
constexpr int kE   = 320;   // embed dim
constexpr int kLH  = 512;   // 2*kH
constexpr int kMLP = 512;

typedef _Float16 h2 __attribute__((ext_vector_type(2)));

__device__ __forceinline__ float fexp2f(float x) {
  float r; asm("v_exp_f32 %0, %1" : "=v"(r) : "v"(x)); return r;
}
__device__ __forceinline__ float frcpf(float x) {
  float r; asm("v_rcp_f32 %0, %1" : "=v"(r) : "v"(x)); return r;
}
__device__ __forceinline__ float sigm(float x) {
  return frcpf(1.0f + fexp2f(-1.4426950408889634f * x));
}
__device__ __forceinline__ float tanh_(float x) {
  // tanh(x) = 1 - 2/(1+e^{2x}); e^{2x} = 2^(x*2*log2(e)). inf-safe at both ends.
  return 1.0f - 2.0f * frcpf(1.0f + fexp2f(2.8853900817779268f * x));
}

__device__ __forceinline__ float fdot2(unsigned int w, unsigned int h, float c) {
#if __has_builtin(__builtin_amdgcn_fdot2)
  return __builtin_amdgcn_fdot2(__builtin_bit_cast(h2, w),
                                __builtin_bit_cast(h2, h), c, false);
#else
  const h2 wv = __builtin_bit_cast(h2, w);
  const h2 hv = __builtin_bit_cast(h2, h);
  return c + (float)wv.x * (float)hv.x + (float)wv.y * (float)hv.y;
#endif
}

__device__ __forceinline__ unsigned int packh2(float a, float b) {
  h2 v; v.x = (_Float16)a; v.y = (_Float16)b;
  return __builtin_bit_cast(unsigned int, v);
}

// ---------------- embedding gather ----------------
__global__ void embed_k(const int* __restrict__ wt, const int* __restrict__ pt,
                        const float* __restrict__ we, const float* __restrict__ pe,
                        float* __restrict__ X) {
  const int t = blockIdx.x;
  const int c = threadIdx.x;  // 0..319
  const int w = wt[t];
  const int p = pt[t];
  X[t * kE + c] = (c < 256) ? we[(size_t)w * 256 + c] : pe[p * 64 + (c - 256)];
}

// ---------------- Whh f32 -> packed f16 (both layers, full GPU) ----------------
__global__ __launch_bounds__(256) void pack_wh_k(
    const float* __restrict__ whh0, const float* __restrict__ whh1,
    unsigned int* __restrict__ wh16) {
  const int idx = blockIdx.x * 256 + threadIdx.x;   // 0 .. 2*262144-1
  const int layer = idx >> 18;
  const int li = idx & 262143;
  const int rowg = li >> 7;                         // d*1024 + row
  const int c2 = li & 127;
  const float* src = (layer ? whh1 : whh0) + (size_t)rowg * kH + c2 * 2;
  wh16[idx] = packh2(src[0], src[1]);
}

// ---------------- generic f32 "NT" GEMM ----------------
template <int BM, int BN, int BK>
__global__ __launch_bounds__(256) void gemm_nt(
    const float* __restrict__ A, int lda,
    const float* __restrict__ B, int ldb,
    const float* __restrict__ b1, const float* __restrict__ b2, float scale,
    float* __restrict__ C, int csm, int csn, int K) {
  const int tid = threadIdx.x;
  const int m0 = blockIdx.y * BM;
  const int n0 = blockIdx.x * BN;
  __shared__ float As[BK][BM];
  __shared__ float Bs[BK][BN];
  const int lm = tid >> 2;
  const int lk = tid & 3;
  const int tx = tid & 15;
  const int ty = tid >> 4;
  float acc[4][4] = {};
  for (int k0 = 0; k0 < K; k0 += BK) {
    const float4 av = *(const float4*)(A + (size_t)(m0 + lm) * lda + k0 + lk * 4);
    const float4 bv = *(const float4*)(B + (size_t)(n0 + lm) * ldb + k0 + lk * 4);
    __syncthreads();
    As[lk * 4 + 0][lm] = av.x; As[lk * 4 + 1][lm] = av.y;
    As[lk * 4 + 2][lm] = av.z; As[lk * 4 + 3][lm] = av.w;
    Bs[lk * 4 + 0][lm] = bv.x; Bs[lk * 4 + 1][lm] = bv.y;
    Bs[lk * 4 + 2][lm] = bv.z; Bs[lk * 4 + 3][lm] = bv.w;
    __syncthreads();
#pragma unroll
    for (int kk = 0; kk < BK; ++kk) {
      const float4 a = *(const float4*)&As[kk][ty * 4];
      const float4 b = *(const float4*)&Bs[kk][tx * 4];
      acc[0][0] = fmaf(a.x, b.x, acc[0][0]);
      acc[0][1] = fmaf(a.x, b.y, acc[0][1]);
      acc[0][2] = fmaf(a.x, b.z, acc[0][2]);
      acc[0][3] = fmaf(a.x, b.w, acc[0][3]);
      acc[1][0] = fmaf(a.y, b.x, acc[1][0]);
      acc[1][1] = fmaf(a.y, b.y, acc[1][1]);
      acc[1][2] = fmaf(a.y, b.z, acc[1][2]);
      acc[1][3] = fmaf(a.y, b.w, acc[1][3]);
      acc[2][0] = fmaf(a.z, b.x, acc[2][0]);
      acc[2][1] = fmaf(a.z, b.y, acc[2][1]);
      acc[2][2] = fmaf(a.z, b.z, acc[2][2]);
      acc[2][3] = fmaf(a.z, b.w, acc[2][3]);
      acc[3][0] = fmaf(a.w, b.x, acc[3][0]);
      acc[3][1] = fmaf(a.w, b.y, acc[3][1]);
      acc[3][2] = fmaf(a.w, b.z, acc[3][2]);
      acc[3][3] = fmaf(a.w, b.w, acc[3][3]);
    }
  }
#pragma unroll
  for (int ii = 0; ii < 4; ++ii) {
#pragma unroll
    for (int jj = 0; jj < 4; ++jj) {
      const int m = m0 + ty * 4 + ii;
      const int n = n0 + tx * 4 + jj;
      float v = acc[ii][jj];
      if (b1) v += b1[n];
      if (b2) v += b2[n];
      C[(size_t)m * csm + (size_t)n * csn] = v * scale;
    }
  }
}

// ---------------- 2-CU-per-direction LSTM scan, own-dot-in-poll-window ----------------
// r12 base (XCD co-location {0,8}/{1,9}, agent-atomic data-as-flag comm) with the
// own-half dot moved INTO the Phase-B latency window:
//   Phase A: only ch==(1-s) waves dot the REMOTE column-half of h(u-1).
//   Sa.
//   Phase B: waves 0-1 (gates): sum pbuf halves + pregate, c/h update, publish
//            own h-half (agent atomic first), write hh16 own half, then each
//            gate wave RELEASE-increments an LDS flag.
//            poller waves (2 ch==(1-s) waves of 8..11): poll peer's h(u).
//            ch==s waves (incl. gate wave s after its gates): ACQUIRE-spin on
//            flag==2(u+1), then dot OWN column-half of h(u) -> pbuf[s].
//   Sb: hh16 = complete h(u); pbuf[s] = own-half partials for step u+1.
// Flag is monotonic (2/step, local LDS) -> no re-arm, no deadlock; pollers and
// own-dot waves are disjoint. pbuf[s] pre-zeroed for u=0 (h(-1)=0).
__global__ __launch_bounds__(1024)
__attribute__((amdgpu_waves_per_eu(4, 4)))
void lstm_scan_2cu(
    const unsigned int* __restrict__ wh16,  // (2,1024,128) packed f16 pairs
    const float* __restrict__ pre,          // (2, kSeq, kG) pregates
    float* __restrict__ out,                // (kSeq, kLH)
    float* __restrict__ comm)               // (2, kSeq, kH) f32, pre-zeroed
{
  const int bx = blockIdx.x;
  int d, s;
  if (bx == 0)      { d = 0; s = 0; }
  else if (bx == 1) { d = 1; s = 0; }
  else if (bx == 8) { d = 0; s = 1; }
  else if (bx == 9) { d = 1; s = 1; }
  else return;                         // co-location dummies exit

  const int t = threadIdx.x;
  const int w = t >> 6;
  const int L = t & 63;
  const int ch = w & 1;                 // column-half this wave dots
  const int r  = (w >> 1) * 64 + L;     // local row 0..511  (= g*128 + j)
  const int g  = r >> 7;
  const int j  = r & 127;
  const int grow = g * kH + s * 128 + j;

  uint4 wr[16];                         // cols [ch*128, +128) of row grow
  {
    const uint4* wp = (const uint4*)wh16 + ((size_t)d * kG + grow) * 32 + ch * 16;
#pragma unroll
    for (int k = 0; k < 16; ++k) wr[k] = wp[k];
  }

  __shared__ __align__(16) _Float16 hh16[kH];  // h(u-1)/h(u), both halves
  __shared__ float pbuf[2][512];
  __shared__ unsigned int gflag;
  ((float*)pbuf)[t] = 0.0f;                    // pbuf[s] must be 0 at u=0
  if (t < 128) ((h2*)hh16)[t] = h2{(_Float16)0.f, (_Float16)0.f};
  if (t == 0) gflag = 0u;
  float c = 0.0f;
  __syncthreads();

  const uint4* hh4 = (const uint4*)hh16;
  float* cm = comm + (size_t)d * kSeq * kH;
  const bool isGateWave = (w < 2);             // waves 0,1 (t<128)
  // pollers: the two waves among 8..11 whose ch == 1-s (no own-dot duty)
  const int pw0 = 8 + (1 - s);
  const int pw1 = 10 + (1 - s);
  const bool isPoll = (w == pw0) || (w == pw1);
  const int re = (1 - s) * 128 + ((w == pw1) ? 64 : 0) + L;  // polled element

  for (int u = 0; u < kSeq; ++u) {
    const int ts = d ? (kSeq - 1 - u) : u;
    // gate threads: issue this step's 4 pregate loads; resolve under phase A
    float pg0 = 0.f, pg1 = 0.f, pg2 = 0.f, pg3 = 0.f;
    if (isGateWave) {
      const float* pp = pre + ((size_t)d * kSeq + ts) * kG + s * 128 + t;
      pg0 = pp[0]; pg1 = pp[256]; pg2 = pp[512]; pg3 = pp[768];
    }
    // ---- Phase A: ch==(1-s) waves dot the REMOTE half of h(u-1) ----
    if (ch != s) {
      const uint4* hp = hh4 + ch * 16;
      float a0 = 0.f, a1 = 0.f, a2 = 0.f, a3 = 0.f;
#pragma unroll
      for (int k = 0; k < 16; ++k) {
        const uint4 hv = hp[k];      // wave-uniform LDS broadcast
        a0 = fdot2(wr[k].x, hv.x, a0);
        a1 = fdot2(wr[k].y, hv.y, a1);
        a2 = fdot2(wr[k].z, hv.z, a2);
        a3 = fdot2(wr[k].w, hv.w, a3);
      }
      pbuf[ch][r] = (a0 + a1) + (a2 + a3);
    }
    __syncthreads();   // Sa: both pbuf halves complete for h(u-1)

    // ---- Phase B: gates || poll || own-half dot (in the latency window) ----
    if (isGateWave) {
      const float gi = pbuf[0][t]       + pbuf[1][t]       + pg0;
      const float gf = pbuf[0][128 + t] + pbuf[1][128 + t] + pg1;
      const float gg = pbuf[0][256 + t] + pbuf[1][256 + t] + pg2;
      const float go = pbuf[0][384 + t] + pbuf[1][384 + t] + pg3;
      const float iv = sigm(gi), fv = sigm(gf);
      const float gv = tanh_(gg), ov = sigm(go);
      c = fv * c + iv * gv;
      const float h = ov * tanh_(c);
      const int e = s * 128 + t;
      __hip_atomic_store(&cm[(size_t)u * kH + e], h + 2.0f,
                         __ATOMIC_RELAXED, __HIP_MEMORY_SCOPE_AGENT);
      hh16[e] = (_Float16)h;
      out[(size_t)ts * kLH + d * kH + e] = h;
      if (L == 0)   // own-half data written -> release one of two flag tokens
        __hip_atomic_fetch_add(&gflag, 1u, __ATOMIC_RELEASE,
                               __HIP_MEMORY_SCOPE_WORKGROUP);
    } else if (isPoll) {
      const float* src = &cm[(size_t)u * kH + re];
      float a = __hip_atomic_load(src, __ATOMIC_RELAXED, __HIP_MEMORY_SCOPE_AGENT);
      float b = __hip_atomic_load(src, __ATOMIC_RELAXED, __HIP_MEMORY_SCOPE_AGENT);
      while (a == 0.0f) {
        a = b;
        b = __hip_atomic_load(src, __ATOMIC_RELAXED, __HIP_MEMORY_SCOPE_AGENT);
      }
      hh16[re] = (_Float16)(a - 2.0f);
    }
    if (ch == s) {
      // own-half dot of h(u) (gate wave s falls through here after its gates)
      const unsigned int want = 2u * (unsigned)(u + 1);
      while (__hip_atomic_load(&gflag, __ATOMIC_ACQUIRE,
                               __HIP_MEMORY_SCOPE_WORKGROUP) < want) {}
      const uint4* hp = hh4 + ch * 16;
      float a0 = 0.f, a1 = 0.f, a2 = 0.f, a3 = 0.f;
#pragma unroll
      for (int k = 0; k < 16; ++k) {
        const uint4 hv = hp[k];
        a0 = fdot2(wr[k].x, hv.x, a0);
        a1 = fdot2(wr[k].y, hv.y, a1);
        a2 = fdot2(wr[k].z, hv.z, a2);
        a3 = fdot2(wr[k].w, hv.w, a3);
      }
      pbuf[ch][r] = (a0 + a1) + (a2 + a3);
    }
    __syncthreads();   // Sb: hh16 = complete h(u); pbuf[s] ready for u+1
  }
}

// ---------------- pair scorer ----------------
__global__ __launch_bounds__(512) void score_k(
    const float* __restrict__ Up, const float* __restrict__ VT,
    const float* __restrict__ wout, const float* __restrict__ bout,
    float* __restrict__ out) {
  const int i = blockIdx.x;
  const int j = threadIdx.x;
  __shared__ float u_sh[kMLP];
  __shared__ float w_sh[kMLP];
  u_sh[j] = Up[(size_t)i * kMLP + j];
  w_sh[j] = wout[j];
  __syncthreads();
  float acc = 0.0f;
#pragma unroll 4
  for (int m = 0; m < kMLP; ++m) {
    const float x = u_sh[m] + VT[(size_t)m * kSeq + j];  // pre-scaled by 2*log2e
    const float th = 1.0f - 2.0f * frcpf(1.0f + fexp2f(x));
    acc = fmaf(th, w_sh[m], acc);
  }
  const float s = acc + bout[0];
  out[(size_t)i * kSeq + j] = (j == i) ? 0.0f : s;
}

extern "C" void kernel_launch(void* const* d_in, const int* in_sizes, int n_in,
                              void* d_out, int out_size, void* d_ws, size_t ws_size,
                              hipStream_t stream) {
  const int*   wt   = (const int*)d_in[0];
  const int*   pt   = (const int*)d_in[1];
  const float* wemb = (const float*)d_in[2];
  const float* pemb = (const float*)d_in[3];
  const float* wih0 = (const float*)d_in[4];
  const float* whh0 = (const float*)d_in[5];
  const float* bih0 = (const float*)d_in[6];
  const float* bhh0 = (const float*)d_in[7];
  const float* wih1 = (const float*)d_in[8];
  const float* whh1 = (const float*)d_in[9];
  const float* bih1 = (const float*)d_in[10];
  const float* bhh1 = (const float*)d_in[11];
  const float* wlin = (const float*)d_in[12];
  const float* blin = (const float*)d_in[13];
  const float* wout = (const float*)d_in[14];
  const float* bout = (const float*)d_in[15];
  float* outp = (float*)d_out;

  float* ws   = (float*)d_ws;
  float* X    = ws;                      // 512*320
  float* PG0  = X + kSeq * kE;           // 2*512*1024
  float* X1   = PG0 + 2 * kSeq * kG;     // 512*512
  float* PG1  = X1 + kSeq * kLH;         // 2*512*1024
  float* LOUT = PG1 + 2 * kSeq * kG;     // 512*512
  float* U    = LOUT + kSeq * kLH;       // 512*512
  float* VT   = U + kSeq * kMLP;         // 512*512
  float* COMM0 = VT + kSeq * kMLP;       // 2*512*256
  float* COMM1 = COMM0 + 2 * kSeq * kH;  // 2*512*256
  unsigned int* WH16 = (unsigned int*)(COMM1 + 2 * kSeq * kH);  // 2*262144

  const float SC = 2.8853900817779268f;  // 2*log2(e), folds tanh scaling

  // zero both layers' comm buffers (data-as-flag; fresh slot per step)
  hipMemsetAsync(COMM0, 0, 2 * 2 * kSeq * kH * sizeof(float), stream);

  embed_k<<<kSeq, kE, 0, stream>>>(wt, pt, wemb, pemb, X);
  pack_wh_k<<<2048, 256, 0, stream>>>(whh0, whh1, WH16);

  for (int d = 0; d < 2; ++d) {
    gemm_nt<64, 64, 16><<<dim3(kG / 64, kSeq / 64), 256, 0, stream>>>(
        X, kE, wih0 + (size_t)d * kG * kE, kE,
        bih0 + d * kG, bhh0 + d * kG, 1.0f,
        PG0 + (size_t)d * kSeq * kG, kG, 1, kE);
  }
  lstm_scan_2cu<<<10, 1024, 0, stream>>>(WH16, PG0, X1, COMM0);

  for (int d = 0; d < 2; ++d) {
    gemm_nt<64, 64, 16><<<dim3(kG / 64, kSeq / 64), 256, 0, stream>>>(
        X1, kLH, wih1 + (size_t)d * kG * kLH, kLH,
        bih1 + d * kG, bhh1 + d * kG, 1.0f,
        PG1 + (size_t)d * kSeq * kG, kG, 1, kLH);
  }
  lstm_scan_2cu<<<10, 1024, 0, stream>>>(WH16 + 2 * kG * 128, PG1, LOUT, COMM1);

  gemm_nt<64, 64, 16><<<dim3(kMLP / 64, kSeq / 64), 256, 0, stream>>>(
      LOUT, kLH, wlin, 2 * kLH, nullptr, nullptr, SC,
      U, kMLP, 1, kLH);
  gemm_nt<64, 64, 16><<<dim3(kMLP / 64, kSeq / 64), 256, 0, stream>>>(
      LOUT, kLH, wlin + kLH, 2 * kLH, blin, nullptr, SC,
      VT, 1, kSeq, kLH);

  score_k<<<kSeq, 512, 0, stream>>>(U, VT, wout, bout, outp);
}

// Round 15
// 1805.815 us; speedup vs baseline: 1.4763x; 1.0472x over previous
//
#include <hip/hip_runtime.h>
#include <cstddef>
#include <cstdint>

constexpr int kSeq = 512;
constexpr int kH   = 256;   // hidden per direction
constexpr int kG   = 1024;  // 4*kH (gates)
constexpr int kE   = 320;   // embed dim
constexpr int kLH  = 512;   // 2*kH
constexpr int kMLP = 512;

typedef _Float16 h2 __attribute__((ext_vector_type(2)));

__device__ __forceinline__ float fexp2f(float x) {
  float r; asm("v_exp_f32 %0, %1" : "=v"(r) : "v"(x)); return r;
}
__device__ __forceinline__ float frcpf(float x) {
  float r; asm("v_rcp_f32 %0, %1" : "=v"(r) : "v"(x)); return r;
}
__device__ __forceinline__ float sigm(float x) {
  return frcpf(1.0f + fexp2f(-1.4426950408889634f * x));
}
__device__ __forceinline__ float tanh_(float x) {
  // tanh(x) = 1 - 2/(1+e^{2x}); e^{2x} = 2^(x*2*log2(e)). inf-safe at both ends.
  return 1.0f - 2.0f * frcpf(1.0f + fexp2f(2.8853900817779268f * x));
}

__device__ __forceinline__ float fdot2(unsigned int w, unsigned int h, float c) {
#if __has_builtin(__builtin_amdgcn_fdot2)
  return __builtin_amdgcn_fdot2(__builtin_bit_cast(h2, w),
                                __builtin_bit_cast(h2, h), c, false);
#else
  const h2 wv = __builtin_bit_cast(h2, w);
  const h2 hv = __builtin_bit_cast(h2, h);
  return c + (float)wv.x * (float)hv.x + (float)wv.y * (float)hv.y;
#endif
}

__device__ __forceinline__ unsigned int packh2(float a, float b) {
  h2 v; v.x = (_Float16)a; v.y = (_Float16)b;
  return __builtin_bit_cast(unsigned int, v);
}

// ---------------- embedding gather ----------------
__global__ void embed_k(const int* __restrict__ wt, const int* __restrict__ pt,
                        const float* __restrict__ we, const float* __restrict__ pe,
                        float* __restrict__ X) {
  const int t = blockIdx.x;
  const int c = threadIdx.x;  // 0..319
  const int w = wt[t];
  const int p = pt[t];
  X[t * kE + c] = (c < 256) ? we[(size_t)w * 256 + c] : pe[p * 64 + (c - 256)];
}

// ---------------- Whh f32 -> packed f16 (both layers, full GPU) ----------------
__global__ __launch_bounds__(256) void pack_wh_k(
    const float* __restrict__ whh0, const float* __restrict__ whh1,
    unsigned int* __restrict__ wh16) {
  const int idx = blockIdx.x * 256 + threadIdx.x;   // 0 .. 2*262144-1
  const int layer = idx >> 18;
  const int li = idx & 262143;
  const int rowg = li >> 7;                         // d*1024 + row
  const int c2 = li & 127;
  const float* src = (layer ? whh1 : whh0) + (size_t)rowg * kH + c2 * 2;
  wh16[idx] = packh2(src[0], src[1]);
}

// ---------------- generic f32 "NT" GEMM ----------------
template <int BM, int BN, int BK>
__global__ __launch_bounds__(256) void gemm_nt(
    const float* __restrict__ A, int lda,
    const float* __restrict__ B, int ldb,
    const float* __restrict__ b1, const float* __restrict__ b2, float scale,
    float* __restrict__ C, int csm, int csn, int K) {
  const int tid = threadIdx.x;
  const int m0 = blockIdx.y * BM;
  const int n0 = blockIdx.x * BN;
  __shared__ float As[BK][BM];
  __shared__ float Bs[BK][BN];
  const int lm = tid >> 2;
  const int lk = tid & 3;
  const int tx = tid & 15;
  const int ty = tid >> 4;
  float acc[4][4] = {};
  for (int k0 = 0; k0 < K; k0 += BK) {
    const float4 av = *(const float4*)(A + (size_t)(m0 + lm) * lda + k0 + lk * 4);
    const float4 bv = *(const float4*)(B + (size_t)(n0 + lm) * ldb + k0 + lk * 4);
    __syncthreads();
    As[lk * 4 + 0][lm] = av.x; As[lk * 4 + 1][lm] = av.y;
    As[lk * 4 + 2][lm] = av.z; As[lk * 4 + 3][lm] = av.w;
    Bs[lk * 4 + 0][lm] = bv.x; Bs[lk * 4 + 1][lm] = bv.y;
    Bs[lk * 4 + 2][lm] = bv.z; Bs[lk * 4 + 3][lm] = bv.w;
    __syncthreads();
#pragma unroll
    for (int kk = 0; kk < BK; ++kk) {
      const float4 a = *(const float4*)&As[kk][ty * 4];
      const float4 b = *(const float4*)&Bs[kk][tx * 4];
      acc[0][0] = fmaf(a.x, b.x, acc[0][0]);
      acc[0][1] = fmaf(a.x, b.y, acc[0][1]);
      acc[0][2] = fmaf(a.x, b.z, acc[0][2]);
      acc[0][3] = fmaf(a.x, b.w, acc[0][3]);
      acc[1][0] = fmaf(a.y, b.x, acc[1][0]);
      acc[1][1] = fmaf(a.y, b.y, acc[1][1]);
      acc[1][2] = fmaf(a.y, b.z, acc[1][2]);
      acc[1][3] = fmaf(a.y, b.w, acc[1][3]);
      acc[2][0] = fmaf(a.z, b.x, acc[2][0]);
      acc[2][1] = fmaf(a.z, b.y, acc[2][1]);
      acc[2][2] = fmaf(a.z, b.z, acc[2][2]);
      acc[2][3] = fmaf(a.z, b.w, acc[2][3]);
      acc[3][0] = fmaf(a.w, b.x, acc[3][0]);
      acc[3][1] = fmaf(a.w, b.y, acc[3][1]);
      acc[3][2] = fmaf(a.w, b.z, acc[3][2]);
      acc[3][3] = fmaf(a.w, b.w, acc[3][3]);
    }
  }
#pragma unroll
  for (int ii = 0; ii < 4; ++ii) {
#pragma unroll
    for (int jj = 0; jj < 4; ++jj) {
      const int m = m0 + ty * 4 + ii;
      const int n = n0 + tx * 4 + jj;
      float v = acc[ii][jj];
      if (b1) v += b1[n];
      if (b2) v += b2[n];
      C[(size_t)m * csm + (size_t)n * csn] = v * scale;
    }
  }
}

// ---------------- 2-CU-per-direction LSTM scan (r12 schedule, leaner dot) ----------------
// 4 workers among 10 blocks: bx {0,8} -> d=0 s=0/1, {1,9} -> d=1 (XCD co-location
// heuristic; correctness via agent-scope atomics regardless of placement).
// Thread t: col-quarter q = t>>8 (wave-uniform), row-pair p = t&255; dots local
// rows {p, p+256} over cols [q*64, q*64+64): 16 weight-uint4, but only 8 h-reads
// per wave (halved LDS broadcast traffic vs r12's row x col-half mapping).
// Per step u (2 barriers):
//   Phase A: all 16 waves dot their col-quarter of h(u-1) -> pbuf[q][row].
//   Sa.
//   Phase B: t<128: gates (sum 4 quarters + pregate), c/h, agent-atomic publish
//            own h-half FIRST; t in [512,640): 4-deep pipelined poll of peer's
//            h(u) (produced concurrently by the peer's Phase B).
//   Sb: hh16 = complete h(u).
// Data-as-flag: fresh slot/step, h+2.0 never 0 bits.
__global__ __launch_bounds__(1024)
__attribute__((amdgpu_waves_per_eu(4, 4)))
void lstm_scan_2cu(
    const unsigned int* __restrict__ wh16,  // (2,1024,128) packed f16 pairs
    const float* __restrict__ pre,          // (2, kSeq, kG) pregates
    float* __restrict__ out,                // (kSeq, kLH)
    float* __restrict__ comm)               // (2, kSeq, kH) f32, pre-zeroed
{
  const int bx = blockIdx.x;
  int d, s;
  if (bx == 0)      { d = 0; s = 0; }
  else if (bx == 1) { d = 1; s = 0; }
  else if (bx == 8) { d = 0; s = 1; }
  else if (bx == 9) { d = 1; s = 1; }
  else return;                         // co-location dummies exit

  const int t = threadIdx.x;
  const int q = t >> 8;                // col-quarter 0..3 (uniform per wave)
  const int p = t & 255;               // row-pair index
  const int r0 = p;                    // local row (gates i/f)
  const int r1 = p + 256;              // local row (gates g/o)
  // local row r -> global gate row: g = r>>7, j = r&127, grow = g*kH + s*128 + j
  const int grow0 = (r0 >> 7) * kH + s * 128 + (r0 & 127);
  const int grow1 = (r1 >> 7) * kH + s * 128 + (r1 & 127);

  uint4 w0[8], w1[8];                  // cols [q*64, q*64+64) of rows grow0/grow1
  {
    const uint4* a = (const uint4*)wh16 + ((size_t)d * kG + grow0) * 32 + q * 8;
    const uint4* b = (const uint4*)wh16 + ((size_t)d * kG + grow1) * 32 + q * 8;
#pragma unroll
    for (int k = 0; k < 8; ++k) { w0[k] = a[k]; w1[k] = b[k]; }
  }

  __shared__ __align__(16) _Float16 hh16[kH];  // h(u-1)/h(u), both halves
  __shared__ float pbuf[4][512];               // per-quarter partials
  if (t < 128) ((h2*)hh16)[t] = h2{(_Float16)0.f, (_Float16)0.f};
  float c = 0.0f;
  __syncthreads();

  const uint4* hh4 = (const uint4*)hh16;       // 32 uint4; quarter q uses [q*8, +8)
  float* cm = comm + (size_t)d * kSeq * kH;
  const bool isGate = (t < 128);
  const bool isPoll = (t >= 512 && t < 640);
  const int re = (1 - s) * 128 + (t - 512);    // element polled (valid if isPoll)

  for (int u = 0; u < kSeq; ++u) {
    const int ts = d ? (kSeq - 1 - u) : u;
    // gate threads: issue this step's 4 pregate loads; resolve under the dot
    float pg0 = 0.f, pg1 = 0.f, pg2 = 0.f, pg3 = 0.f;
    if (isGate) {
      const float* pp = pre + ((size_t)d * kSeq + ts) * kG + s * 128 + t;
      pg0 = pp[0]; pg1 = pp[256]; pg2 = pp[512]; pg3 = pp[768];
    }
    // ---- Phase A: dot col-quarter q of h(u-1) for rows r0, r1 ----
    {
      const uint4* hp = hh4 + q * 8;
      float a0 = 0.f, a1 = 0.f, a2 = 0.f, a3 = 0.f;
      float b0 = 0.f, b1 = 0.f, b2 = 0.f, b3 = 0.f;
#pragma unroll
      for (int k = 0; k < 8; ++k) {
        const uint4 hv = hp[k];      // wave-uniform LDS broadcast (8 reads/wave)
        a0 = fdot2(w0[k].x, hv.x, a0);
        a1 = fdot2(w0[k].y, hv.y, a1);
        a2 = fdot2(w0[k].z, hv.z, a2);
        a3 = fdot2(w0[k].w, hv.w, a3);
        b0 = fdot2(w1[k].x, hv.x, b0);
        b1 = fdot2(w1[k].y, hv.y, b1);
        b2 = fdot2(w1[k].z, hv.z, b2);
        b3 = fdot2(w1[k].w, hv.w, b3);
      }
      pbuf[q][r0] = (a0 + a1) + (a2 + a3);
      pbuf[q][r1] = (b0 + b1) + (b2 + b3);
    }
    __syncthreads();   // Sa: all quarter-partials complete

    // ---- Phase B: gates (own half) || 4-deep poll of peer's h(u) ----
    if (isGate) {
      const float gi = ((pbuf[0][t]       + pbuf[1][t])       + (pbuf[2][t]       + pbuf[3][t]))       + pg0;
      const float gf = ((pbuf[0][128 + t] + pbuf[1][128 + t]) + (pbuf[2][128 + t] + pbuf[3][128 + t])) + pg1;
      const float gg = ((pbuf[0][256 + t] + pbuf[1][256 + t]) + (pbuf[2][256 + t] + pbuf[3][256 + t])) + pg2;
      const float go = ((pbuf[0][384 + t] + pbuf[1][384 + t]) + (pbuf[2][384 + t] + pbuf[3][384 + t])) + pg3;
      const float iv = sigm(gi), fv = sigm(gf);
      const float gv = tanh_(gg), ov = sigm(go);
      c = fv * c + iv * gv;
      const float h = ov * tanh_(c);
      const int e = s * 128 + t;
      __hip_atomic_store(&cm[(size_t)u * kH + e], h + 2.0f,
                         __ATOMIC_RELAXED, __HIP_MEMORY_SCOPE_AGENT);
      hh16[e] = (_Float16)h;
      out[(size_t)ts * kLH + d * kH + e] = h;
    } else if (isPoll) {
      const float* src = &cm[(size_t)u * kH + re];
      float a0 = __hip_atomic_load(src, __ATOMIC_RELAXED, __HIP_MEMORY_SCOPE_AGENT);
      float a1 = __hip_atomic_load(src, __ATOMIC_RELAXED, __HIP_MEMORY_SCOPE_AGENT);
      float a2 = __hip_atomic_load(src, __ATOMIC_RELAXED, __HIP_MEMORY_SCOPE_AGENT);
      float a3 = __hip_atomic_load(src, __ATOMIC_RELAXED, __HIP_MEMORY_SCOPE_AGENT);
      float v;
      for (;;) {
        if (a0 != 0.0f) { v = a0; break; }
        a0 = a1; a1 = a2; a2 = a3;
        a3 = __hip_atomic_load(src, __ATOMIC_RELAXED, __HIP_MEMORY_SCOPE_AGENT);
      }
      hh16[re] = (_Float16)(v - 2.0f);
    }
    __syncthreads();   // Sb: hh16 = complete h(u)
  }
}

// ---------------- pair scorer ----------------
__global__ __launch_bounds__(512) void score_k(
    const float* __restrict__ Up, const float* __restrict__ VT,
    const float* __restrict__ wout, const float* __restrict__ bout,
    float* __restrict__ out) {
  const int i = blockIdx.x;
  const int j = threadIdx.x;
  __shared__ float u_sh[kMLP];
  __shared__ float w_sh[kMLP];
  u_sh[j] = Up[(size_t)i * kMLP + j];
  w_sh[j] = wout[j];
  __syncthreads();
  float acc = 0.0f;
#pragma unroll 4
  for (int m = 0; m < kMLP; ++m) {
    const float x = u_sh[m] + VT[(size_t)m * kSeq + j];  // pre-scaled by 2*log2e
    const float th = 1.0f - 2.0f * frcpf(1.0f + fexp2f(x));
    acc = fmaf(th, w_sh[m], acc);
  }
  const float s = acc + bout[0];
  out[(size_t)i * kSeq + j] = (j == i) ? 0.0f : s;
}

extern "C" void kernel_launch(void* const* d_in, const int* in_sizes, int n_in,
                              void* d_out, int out_size, void* d_ws, size_t ws_size,
                              hipStream_t stream) {
  const int*   wt   = (const int*)d_in[0];
  const int*   pt   = (const int*)d_in[1];
  const float* wemb = (const float*)d_in[2];
  const float* pemb = (const float*)d_in[3];
  const float* wih0 = (const float*)d_in[4];
  const float* whh0 = (const float*)d_in[5];
  const float* bih0 = (const float*)d_in[6];
  const float* bhh0 = (const float*)d_in[7];
  const float* wih1 = (const float*)d_in[8];
  const float* whh1 = (const float*)d_in[9];
  const float* bih1 = (const float*)d_in[10];
  const float* bhh1 = (const float*)d_in[11];
  const float* wlin = (const float*)d_in[12];
  const float* blin = (const float*)d_in[13];
  const float* wout = (const float*)d_in[14];
  const float* bout = (const float*)d_in[15];
  float* outp = (float*)d_out;

  float* ws   = (float*)d_ws;
  float* X    = ws;                      // 512*320
  float* PG0  = X + kSeq * kE;           // 2*512*1024
  float* X1   = PG0 + 2 * kSeq * kG;     // 512*512
  float* PG1  = X1 + kSeq * kLH;         // 2*512*1024
  float* LOUT = PG1 + 2 * kSeq * kG;     // 512*512
  float* U    = LOUT + kSeq * kLH;       // 512*512
  float* VT   = U + kSeq * kMLP;         // 512*512
  float* COMM0 = VT + kSeq * kMLP;       // 2*512*256
  float* COMM1 = COMM0 + 2 * kSeq * kH;  // 2*512*256
  unsigned int* WH16 = (unsigned int*)(COMM1 + 2 * kSeq * kH);  // 2*262144

  const float SC = 2.8853900817779268f;  // 2*log2(e), folds tanh scaling

  // zero both layers' comm buffers (data-as-flag; fresh slot per step)
  hipMemsetAsync(COMM0, 0, 2 * 2 * kSeq * kH * sizeof(float), stream);

  embed_k<<<kSeq, kE, 0, stream>>>(wt, pt, wemb, pemb, X);
  pack_wh_k<<<2048, 256, 0, stream>>>(whh0, whh1, WH16);

  for (int d = 0; d < 2; ++d) {
    gemm_nt<64, 64, 16><<<dim3(kG / 64, kSeq / 64), 256, 0, stream>>>(
        X, kE, wih0 + (size_t)d * kG * kE, kE,
        bih0 + d * kG, bhh0 + d * kG, 1.0f,
        PG0 + (size_t)d * kSeq * kG, kG, 1, kE);
  }
  lstm_scan_2cu<<<10, 1024, 0, stream>>>(WH16, PG0, X1, COMM0);

  for (int d = 0; d < 2; ++d) {
    gemm_nt<64, 64, 16><<<dim3(kG / 64, kSeq / 64), 256, 0, stream>>>(
        X1, kLH, wih1 + (size_t)d * kG * kLH, kLH,
        bih1 + d * kG, bhh1 + d * kG, 1.0f,
        PG1 + (size_t)d * kSeq * kG, kG, 1, kLH);
  }
  lstm_scan_2cu<<<10, 1024, 0, stream>>>(WH16 + 2 * kG * 128, PG1, LOUT, COMM1);

  gemm_nt<64, 64, 16><<<dim3(kMLP / 64, kSeq / 64), 256, 0, stream>>>(
      LOUT, kLH, wlin, 2 * kLH, nullptr, nullptr, SC,
      U, kMLP, 1, kLH);
  gemm_nt<64, 64, 16><<<dim3(kMLP / 64, kSeq / 64), 256, 0, stream>>>(
      LOUT, kLH, wlin + kLH, 2 * kLH, blin, nullptr, SC,
      VT, 1, kSeq, kLH);

  score_k<<<kSeq, 512, 0, stream>>>(U, VT, wout, bout, outp);
}